// Round 18
// baseline (219.528 us; speedup 1.0000x reference)
//
#include <hip/hip_runtime.h>

// Problem: B=64, C=256, H=W=32 -> N=1024 positions, 32 groups.
// Pipeline: GN(+weight convert fused) -> qkv proj -> attention -> out proj -> residual.
// All matmuls in bf16 MFMA (16x16x32). q scaled by C^-0.5=1/16 folded into wq/bq.

#define BB 64
#define CC 256
#define NN 1024

typedef float  floatx4  __attribute__((ext_vector_type(4)));
typedef short  shortx8  __attribute__((ext_vector_type(8)));
typedef unsigned short ushortx4 __attribute__((ext_vector_type(4)));
typedef unsigned short ushortx8 __attribute__((ext_vector_type(8)));

__device__ __forceinline__ unsigned short f2bf(float f) {
  union { float f; unsigned int u; } cv; cv.f = f;
  unsigned int u = cv.u;
  u += 0x7fffu + ((u >> 16) & 1u);
  return (unsigned short)(u >> 16);
}

__device__ __forceinline__ floatx4 mfma16(shortx8 a, shortx8 b, floatx4 c) {
  return __builtin_amdgcn_mfma_f32_16x16x32_bf16(a, b, c, 0, 0, 0);
}

// async global->LDS, 16B per lane. LDS dest = wave-uniform base + lane*16 (linear);
// swizzling is done on the GLOBAL source address (rule #21: both-sides-or-neither).
__device__ __forceinline__ void gload16(const unsigned short* g, unsigned short* s) {
  __builtin_amdgcn_global_load_lds(
      reinterpret_cast<const __attribute__((address_space(1))) void*>(
          (unsigned long long)g),
      reinterpret_cast<__attribute__((address_space(3))) void*>(
          (unsigned int)(unsigned long long)s),
      16, 0, 0);
}

__device__ __forceinline__ void barrier_raw() {
  asm volatile("" ::: "memory");
  __builtin_amdgcn_s_barrier();
  asm volatile("" ::: "memory");
}

// ds_write -> barrier -> ds_read ordering (cross-lane dep the compiler can't see)
__device__ __forceinline__ void bar_lds() {
  asm volatile("s_waitcnt lgkmcnt(0)" ::: "memory");
  __builtin_amdgcn_sched_barrier(0);
  barrier_raw();
}

// K-tile row permutation (32-key tile): LDS row rho holds key k0 + sigma32(rho),
// sigma32(kt*16 + h*4 + r) = h*8 + kt*4 + r  -> lane (h,lo)'s QK outputs are exactly
// the keys PV's A-fragment needs (k = h*8 + j): P->PV is a pure register rename.
__device__ __forceinline__ int sigma32(int r) {
  return (((r >> 2) & 3) << 3) + (((r >> 4) & 1) << 2) + (r & 3);
}

// ---------------- GroupNorm -> h_t (B, N, C) bf16, with weight-convert fused ----------------
// blocks x<32: GN for (group=x, batch=y). blocks x>=32: weight conversion (1088 slots >= 1027).
__global__ __launch_bounds__(256) void gn_kernel(const float* __restrict__ x,
                                                 const float* __restrict__ gw,
                                                 const float* __restrict__ gb,
                                                 unsigned short* __restrict__ h_t,
                                                 const float* __restrict__ wq, const float* __restrict__ bq,
                                                 const float* __restrict__ wk, const float* __restrict__ bk,
                                                 const float* __restrict__ wv, const float* __restrict__ bv,
                                                 const float* __restrict__ wo,
                                                 unsigned short* __restrict__ wqkv,
                                                 unsigned short* __restrict__ wo_bf,
                                                 float* __restrict__ bqkv) {
  if (blockIdx.x >= 32) {
    // ---- weight conversion path ----
    int cid = (blockIdx.x - 32) * 64 + blockIdx.y;
    int i = cid * 256 + threadIdx.x;
    if (i < 196608) {
      int o = i >> 8, c = i & 255;
      float val;
      if (o < 256)      val = wq[o * 256 + c] * 0.0625f;
      else if (o < 512) val = wk[(o - 256) * 256 + c];
      else              val = wv[(o - 512) * 256 + c];
      wqkv[i] = f2bf(val);
    } else if (i < 262144) {
      int j = i - 196608;
      wo_bf[j] = f2bf(wo[j]);
    } else if (i < 262912) {
      int o = i - 262144;
      float val;
      if (o < 256)      val = bq[o] * 0.0625f;
      else if (o < 512) val = bk[o - 256];
      else              val = bv[o - 512];
      bqkv[o] = val;
    }
    return;
  }
  // ---- GroupNorm path ----
  int g = blockIdx.x, b = blockIdx.y;
  int t = threadIdx.x;
  const float* xb = x + ((size_t)b * CC + g * 8) * NN;

  float vals[8][4];
  float s = 0.f, sq = 0.f;
#pragma unroll
  for (int cc = 0; cc < 8; cc++) {
    floatx4 v4 = *(const floatx4*)(xb + cc * NN + t * 4);
#pragma unroll
    for (int j = 0; j < 4; j++) {
      vals[cc][j] = v4[j];
      s += v4[j];
      sq += v4[j] * v4[j];
    }
  }
#pragma unroll
  for (int d = 1; d < 64; d <<= 1) {
    s  += __shfl_xor(s, d);
    sq += __shfl_xor(sq, d);
  }
  __shared__ float ssum[4], ssq[4];
  int w = t >> 6;
  if ((t & 63) == 0) { ssum[w] = s; ssq[w] = sq; }
  __syncthreads();
  s  = ssum[0] + ssum[1] + ssum[2] + ssum[3];
  sq = ssq[0] + ssq[1] + ssq[2] + ssq[3];
  float mean = s * (1.f / 8192.f);
  float var  = sq * (1.f / 8192.f) - mean * mean;
  float rstd = rsqrtf(var + 1e-5f);

  float gam[8], bet[8];
#pragma unroll
  for (int cc = 0; cc < 8; cc++) {
    float gm = gw[g * 8 + cc] * rstd;
    gam[cc] = gm;
    bet[cc] = gb[g * 8 + cc] - mean * gm;
  }
  unsigned short* hb = h_t + (size_t)b * NN * CC + g * 8;
#pragma unroll
  for (int j = 0; j < 4; j++) {
    ushortx8 pk;
#pragma unroll
    for (int cc = 0; cc < 8; cc++) pk[cc] = f2bf(vals[cc][j] * gam[cc] + bet[cc]);
    *(ushortx8*)(hb + (size_t)(t * 4 + j) * CC) = pk;
  }
}

// ---------------- QKV GEMM v3: LDS-staged, A-frags in registers, q/k repack ----------------
__global__ __launch_bounds__(512, 4) void qkv_gemm(const unsigned short* __restrict__ h_t,
                                                   const unsigned short* __restrict__ wqkv,
                                                   const float* __restrict__ bqkv,
                                                   unsigned short* __restrict__ q_t,
                                                   unsigned short* __restrict__ k_t,
                                                   unsigned short* __restrict__ v) {
  __shared__ __align__(16) unsigned short sM[32768];      // 64KB
  __shared__ __align__(16) unsigned short sRep[32 * 136]; // v repack, 272B rows (16B-mult)
  int rb = blockIdx.x, b = blockIdx.y;
  int t = threadIdx.x, w = t >> 6, l = t & 63, lo = l & 15, h = l >> 4;
  int rowg = w >> 1, colg = w & 1;
  const unsigned short* A = h_t + ((size_t)b * NN + rb * 128) * CC;

  int srow_w = w * 2 + (l >> 5);   // staging row (+ i*16)
  int schunk = l & 31;

  // ---- stage A tile 128x256 ----
#pragma unroll
  for (int i = 0; i < 8; i++) {
    int row = i * 16 + srow_w;
    gload16(A + (size_t)row * CC + ((schunk ^ (row & 7)) << 3),
            &sM[(i * 16 + w * 2) << 8]);
  }
  asm volatile("s_waitcnt vmcnt(0)" ::: "memory");
  barrier_raw();

  // ---- extract A-frags to regs (a[i][ch], rows rowg*32 + i*16 + lo) ----
  shortx8 a[2][8];
#pragma unroll
  for (int i = 0; i < 2; i++) {
    int row = rowg * 32 + i * 16 + lo;
#pragma unroll
    for (int ch = 0; ch < 8; ch++)
      a[i][ch] = *(const shortx8*)(&sM[(row << 8) + (((ch * 4 + h) ^ (row & 7)) << 3)]);
  }
  bar_lds();   // sA fully consumed -> LDS reusable for W

  // ---- stage W chunk 0 into buf 0 ----
#pragma unroll
  for (int i = 0; i < 4; i++) {
    int row = i * 16 + srow_w;
    gload16(wqkv + (size_t)row * CC + ((schunk ^ (row & 7)) << 3),
            &sM[(i * 16 + w * 2) << 8]);
  }

  floatx4 zero4 = {0.f, 0.f, 0.f, 0.f};
  for (int c = 0; c < 12; c++) {
    int cb = (c & 1) << 14;
    if (c < 11) {
      int nb = ((c + 1) & 1) << 14;
#pragma unroll
      for (int i = 0; i < 4; i++) {
        int row = i * 16 + srow_w;
        gload16(wqkv + (size_t)((c + 1) * 64 + row) * CC + ((schunk ^ (row & 7)) << 3),
                &sM[nb + ((i * 16 + w * 2) << 8)]);
      }
      asm volatile("s_waitcnt vmcnt(4)" ::: "memory");
    } else {
      asm volatile("s_waitcnt vmcnt(0)" ::: "memory");
    }
    barrier_raw();   // W chunk c visible to all waves

    floatx4 acc[2][2];
    acc[0][0] = zero4; acc[0][1] = zero4; acc[1][0] = zero4; acc[1][1] = zero4;
    int r0 = colg * 32 + lo, r1 = colg * 32 + 16 + lo;
    __builtin_amdgcn_s_setprio(1);
#pragma unroll
    for (int ch = 0; ch < 8; ch++) {
      shortx8 b0 = *(const shortx8*)(&sM[cb + (r0 << 8) + (((ch * 4 + h) ^ (r0 & 7)) << 3)]);
      shortx8 b1 = *(const shortx8*)(&sM[cb + (r1 << 8) + (((ch * 4 + h) ^ (r1 & 7)) << 3)]);
      acc[0][0] = mfma16(a[0][ch], b0, acc[0][0]);
      acc[0][1] = mfma16(a[0][ch], b1, acc[0][1]);
      acc[1][0] = mfma16(a[1][ch], b0, acc[1][0]);
      acc[1][1] = mfma16(a[1][ch], b1, acc[1][1]);
    }
    __builtin_amdgcn_s_setprio(0);

    // ---- epilogue for chunk c ----
    if (c < 8) {
      unsigned short* dst = (c < 4) ? q_t : k_t;
      bar_lds();                         // all waves done reading W chunk c (cb region)
      unsigned short* sQK = &sM[cb];     // reuse 32KB as [128][72]-short repack buffer
#pragma unroll
      for (int i = 0; i < 2; i++) {
#pragma unroll
        for (int j = 0; j < 2; j++) {
          float bias = bqkv[(c << 6) + colg * 32 + j * 16 + lo];
          int o_l = colg * 32 + j * 16 + lo;
#pragma unroll
          for (int r = 0; r < 4; r++) {
            int n_l = rowg * 32 + i * 16 + h * 4 + r;
            sQK[n_l * 72 + o_l] = f2bf(acc[i][j][r] + bias);
          }
        }
      }
      bar_lds();                         // repack writes visible
#pragma unroll
      for (int p = 0; p < 2; p++) {
        int slot = p * 512 + t;
        int n_l = slot >> 3, sg = (slot & 7) << 3;
        ushortx8 vv = *(const ushortx8*)(&sQK[n_l * 72 + sg]);
        *(ushortx8*)(dst + ((size_t)b * NN + rb * 128 + n_l) * CC + ((c & 3) << 6) + sg) = vv;
      }
      bar_lds();                         // reads done before c+2's staging overwrites cb
    } else {
      int vch0 = (c - 8) << 6;
#pragma unroll
      for (int half = 0; half < 2; half++) {
        if (colg == half) {
#pragma unroll
          for (int i = 0; i < 2; i++) {
#pragma unroll
            for (int j = 0; j < 2; j++) {
              float bias = bqkv[512 + vch0 + half * 32 + j * 16 + lo];
              ushortx4 pk;
#pragma unroll
              for (int r = 0; r < 4; r++) pk[r] = f2bf(acc[i][j][r] + bias);
              *(ushortx4*)(&sRep[(j * 16 + lo) * 136 + rowg * 32 + i * 16 + h * 4]) = pk;
            }
          }
        }
        bar_lds();
        int o_l = t >> 4, nseg = (t & 15) << 3;
        ushortx8 vv = *(const ushortx8*)(&sRep[o_l * 136 + nseg]);
        *(ushortx8*)(v + ((size_t)b * CC + vch0 + half * 32 + o_l) * NN + rb * 128 + nseg) = vv;
        bar_lds();
      }
    }
  }
}

// ---------------- Flash attention v13: 2-tile unrolled body, 4-buffer LDS (128KB) ----------------
// 8-wave blocks, grid 256 (1 block/CU). Tiles 2j,2j+1 per body with interleavable chains
// QK(a),QK(b),SM(a),PV(a),SM(b),PV(b): QK(b) fills the MFMA pipe under SM(a)'s VALU wait;
// SM(b) runs under PV(a)'s MFMAs. Buffers: tile kb -> buf kb&3 (K@0, V@32768 shorts).
// 8 loads/wave/body; vmcnt(8) = own tiles 2j,2j+1 landed, next 8 in flight. 2 barriers/body.
__global__ __launch_bounds__(512, 2) void flash_kernel(const unsigned short* __restrict__ q_t,
                                                       const unsigned short* __restrict__ k_t,
                                                       const unsigned short* __restrict__ v,
                                                       unsigned short* __restrict__ attn_t) {
  __shared__ __align__(16) unsigned short sMem[65536];   // 128KB: K0..K3 @0, V0..V3 @32768 (shorts)
  int bid = blockIdx.x;                       // 0..255
  int wgid = ((bid & 7) << 5) + (bid >> 3);   // bijective XCD swizzle: batch pinned to one XCD
  int b = wgid >> 2, qblk = wgid & 3;
  int t = threadIdx.x, w = t >> 6, l = t & 63, lo = l & 15, h = l >> 4;
  const unsigned short* qtb = q_t + (size_t)b * NN * CC;
  const unsigned short* ktb = k_t + (size_t)b * NN * CC;
  const unsigned short* vb  = v   + (size_t)b * CC * NN;
  int qbase = qblk * 256 + w * 32;            // frag A rows qbase.., frag B rows qbase+16..

  shortx8 qfA[8], qfB[8];
#pragma unroll
  for (int ch = 0; ch < 8; ch++) {
    qfA[ch] = *(const shortx8*)(qtb + (size_t)(qbase + lo) * CC + ch * 32 + h * 8);
    qfB[ch] = *(const shortx8*)(qtb + (size_t)(qbase + 16 + lo) * CC + ch * 32 + h * 8);
  }

  floatx4 zero4 = {0.f, 0.f, 0.f, 0.f};
  floatx4 oA[16], oB[16];
#pragma unroll
  for (int i = 0; i < 16; i++) { oA[i] = zero4; oB[i] = zero4; }
  float mA = -1e30f, lsA = 0.f, mB = -1e30f, lsB = 0.f;   // lsA/lsB are per-lane partials

  // staging geometry (per wave, 4 loads/tile: 2 K + 2 V across 8 waves)
  int krow_l = (w << 2) + (l >> 5);   // + i*2  : K rows w*4 .. w*4+3
  int kchunk = l & 31;
  int vrow_l = (w << 5) + (l >> 2);   // + i*16 : V rows w*32 .. w*32+31
  int vchunk = l & 3;

  // prologue: stage tiles 0,1 into bufs 0,1
#pragma unroll
  for (int tt = 0; tt < 2; tt++) {
    int k0 = tt << 5;
#pragma unroll
    for (int i = 0; i < 2; i++) {
      int row = krow_l + i * 2;
      gload16(ktb + (size_t)(k0 + sigma32(row)) * CC + ((kchunk ^ (row & 7)) << 3),
              &sMem[(tt << 13) + (((w << 2) + i * 2) << 8)]);
    }
#pragma unroll
    for (int i = 0; i < 2; i++) {
      int row = vrow_l + i * 16;
      gload16(vb + (size_t)row * NN + k0 + ((vchunk ^ ((row >> 1) & 3)) << 3),
              &sMem[32768 + (tt << 13) + (((w << 5) + i * 16) << 5)]);
    }
  }

  for (int j = 0; j < 16; j++) {
    if (j < 15) {
      // stage tiles 2j+2, 2j+3 into bufs (2j+2)&3, (2j+3)&3 (computed in body j-1; safe
      // after body j-1's trailing barrier)
#pragma unroll
      for (int tt = 0; tt < 2; tt++) {
        int kbn = 2 * j + 2 + tt;
        int k0n = kbn << 5;
        int bufn = kbn & 3;
#pragma unroll
        for (int i = 0; i < 2; i++) {
          int row = krow_l + i * 2;
          gload16(ktb + (size_t)(k0n + sigma32(row)) * CC + ((kchunk ^ (row & 7)) << 3),
                  &sMem[(bufn << 13) + (((w << 2) + i * 2) << 8)]);
        }
#pragma unroll
        for (int i = 0; i < 2; i++) {
          int row = vrow_l + i * 16;
          gload16(vb + (size_t)row * NN + k0n + ((vchunk ^ ((row >> 1) & 3)) << 3),
                  &sMem[32768 + (bufn << 13) + (((w << 5) + i * 16) << 5)]);
        }
      }
      asm volatile("s_waitcnt vmcnt(8)" ::: "memory");   // own tiles 2j,2j+1 landed
    } else {
      asm volatile("s_waitcnt vmcnt(0)" ::: "memory");
    }
    barrier_raw();   // all waves' tiles 2j,2j+1 visible

    int kBa = ((2 * j) & 3) << 13;
    int kBb = ((2 * j + 1) & 3) << 13;
    int vBa = 32768 + (((2 * j) & 3) << 13);
    int vBb = 32768 + (((2 * j + 1) & 3) << 13);

    // ---- QK(a) and QK(b): independent MFMA streams ----
    floatx4 sAa[2], sBa[2], sAb[2], sBb[2];
#pragma unroll
    for (int i = 0; i < 2; i++) { sAa[i] = zero4; sBa[i] = zero4; sAb[i] = zero4; sBb[i] = zero4; }
    __builtin_amdgcn_s_setprio(1);
#pragma unroll
    for (int kt = 0; kt < 2; kt++) {
      const unsigned short* kp = &sMem[kBa + ((kt * 16 + lo) << 8)];
#pragma unroll
      for (int ch = 0; ch < 8; ch++) {
        shortx8 kf = *(const shortx8*)(kp + (((ch * 4 + h) ^ (lo & 7)) << 3));
        sAa[kt] = mfma16(kf, qfA[ch], sAa[kt]);
        sBa[kt] = mfma16(kf, qfB[ch], sBa[kt]);
      }
    }
#pragma unroll
    for (int kt = 0; kt < 2; kt++) {
      const unsigned short* kp = &sMem[kBb + ((kt * 16 + lo) << 8)];
#pragma unroll
      for (int ch = 0; ch < 8; ch++) {
        shortx8 kf = *(const shortx8*)(kp + (((ch * 4 + h) ^ (lo & 7)) << 3));
        sAb[kt] = mfma16(kf, qfA[ch], sAb[kt]);
        sBb[kt] = mfma16(kf, qfB[ch], sBb[kt]);
      }
    }
    __builtin_amdgcn_s_setprio(0);

    // ---- SM(a): tile 2j softmax (frag A then frag B), then PV(a), then SM(b), PV(b) ----
    unsigned int pkAa[2][2], pkBa[2][2], pkAb[2][2], pkBb[2][2];
    {
      float pmax = fmaxf(fmaxf(fmaxf(sAa[0][0], sAa[0][1]), fmaxf(sAa[0][2], sAa[0][3])),
                         fmaxf(fmaxf(sAa[1][0], sAa[1][1]), fmaxf(sAa[1][2], sAa[1][3])));
      if (!__all(pmax - mA <= 8.f)) {
        pmax = fmaxf(pmax, __shfl_xor(pmax, 16));
        pmax = fmaxf(pmax, __shfl_xor(pmax, 32));
        float mn = fmaxf(mA, pmax);
        float alpha = __expf(mA - mn);
        mA = mn;
        lsA *= alpha;
#pragma unroll
        for (int r = 0; r < 4; r++) {
          float ar = __shfl(alpha, (h << 4) + (h << 2) + r);
#pragma unroll
          for (int cbi = 0; cbi < 16; cbi++) oA[cbi][r] *= ar;
        }
      }
      float rs = 0.f;
#pragma unroll
      for (int kt = 0; kt < 2; kt++) {
        float p0 = __expf(sAa[kt][0] - mA);
        float p1 = __expf(sAa[kt][1] - mA);
        float p2 = __expf(sAa[kt][2] - mA);
        float p3 = __expf(sAa[kt][3] - mA);
        rs += (p0 + p1) + (p2 + p3);
        pkAa[kt][0] = (unsigned)f2bf(p0) | ((unsigned)f2bf(p1) << 16);
        pkAa[kt][1] = (unsigned)f2bf(p2) | ((unsigned)f2bf(p3) << 16);
      }
      lsA += rs;
    }
    {
      float pmax = fmaxf(fmaxf(fmaxf(sBa[0][0], sBa[0][1]), fmaxf(sBa[0][2], sBa[0][3])),
                         fmaxf(fmaxf(sBa[1][0], sBa[1][1]), fmaxf(sBa[1][2], sBa[1][3])));
      if (!__all(pmax - mB <= 8.f)) {
        pmax = fmaxf(pmax, __shfl_xor(pmax, 16));
        pmax = fmaxf(pmax, __shfl_xor(pmax, 32));
        float mn = fmaxf(mB, pmax);
        float alpha = __expf(mB - mn);
        mB = mn;
        lsB *= alpha;
#pragma unroll
        for (int r = 0; r < 4; r++) {
          float ar = __shfl(alpha, (h << 4) + (h << 2) + r);
#pragma unroll
          for (int cbi = 0; cbi < 16; cbi++) oB[cbi][r] *= ar;
        }
      }
      float rs = 0.f;
#pragma unroll
      for (int kt = 0; kt < 2; kt++) {
        float p0 = __expf(sBa[kt][0] - mB);
        float p1 = __expf(sBa[kt][1] - mB);
        float p2 = __expf(sBa[kt][2] - mB);
        float p3 = __expf(sBa[kt][3] - mB);
        rs += (p0 + p1) + (p2 + p3);
        pkBa[kt][0] = (unsigned)f2bf(p0) | ((unsigned)f2bf(p1) << 16);
        pkBa[kt][1] = (unsigned)f2bf(p2) | ((unsigned)f2bf(p3) << 16);
      }
      lsB += rs;
    }
    // ---- PV(a) ----
    {
      union { unsigned int u[4]; shortx8 v; } paA, paB;
      paA.u[0] = pkAa[0][0]; paA.u[1] = pkAa[0][1];
      paA.u[2] = pkAa[1][0]; paA.u[3] = pkAa[1][1];
      paB.u[0] = pkBa[0][0]; paB.u[1] = pkBa[0][1];
      paB.u[2] = pkBa[1][0]; paB.u[3] = pkBa[1][1];
      __builtin_amdgcn_s_setprio(1);
#pragma unroll
      for (int cbi = 0; cbi < 16; cbi++) {
        int row = (cbi << 4) + lo;
        shortx8 vf = *(const shortx8*)(&sMem[vBa + (row << 5) +
                                             ((h ^ ((row >> 1) & 3)) << 3)]);
        oA[cbi] = mfma16(paA.v, vf, oA[cbi]);
        oB[cbi] = mfma16(paB.v, vf, oB[cbi]);
      }
      __builtin_amdgcn_s_setprio(0);
    }
    // ---- SM(b): tile 2j+1 ----
    {
      float pmax = fmaxf(fmaxf(fmaxf(sAb[0][0], sAb[0][1]), fmaxf(sAb[0][2], sAb[0][3])),
                         fmaxf(fmaxf(sAb[1][0], sAb[1][1]), fmaxf(sAb[1][2], sAb[1][3])));
      if (!__all(pmax - mA <= 8.f)) {
        pmax = fmaxf(pmax, __shfl_xor(pmax, 16));
        pmax = fmaxf(pmax, __shfl_xor(pmax, 32));
        float mn = fmaxf(mA, pmax);
        float alpha = __expf(mA - mn);
        mA = mn;
        lsA *= alpha;
#pragma unroll
        for (int r = 0; r < 4; r++) {
          float ar = __shfl(alpha, (h << 4) + (h << 2) + r);
#pragma unroll
          for (int cbi = 0; cbi < 16; cbi++) oA[cbi][r] *= ar;
        }
      }
      float rs = 0.f;
#pragma unroll
      for (int kt = 0; kt < 2; kt++) {
        float p0 = __expf(sAb[kt][0] - mA);
        float p1 = __expf(sAb[kt][1] - mA);
        float p2 = __expf(sAb[kt][2] - mA);
        float p3 = __expf(sAb[kt][3] - mA);
        rs += (p0 + p1) + (p2 + p3);
        pkAb[kt][0] = (unsigned)f2bf(p0) | ((unsigned)f2bf(p1) << 16);
        pkAb[kt][1] = (unsigned)f2bf(p2) | ((unsigned)f2bf(p3) << 16);
      }
      lsA += rs;
    }
    {
      float pmax = fmaxf(fmaxf(fmaxf(sBb[0][0], sBb[0][1]), fmaxf(sBb[0][2], sBb[0][3])),
                         fmaxf(fmaxf(sBb[1][0], sBb[1][1]), fmaxf(sBb[1][2], sBb[1][3])));
      if (!__all(pmax - mB <= 8.f)) {
        pmax = fmaxf(pmax, __shfl_xor(pmax, 16));
        pmax = fmaxf(pmax, __shfl_xor(pmax, 32));
        float mn = fmaxf(mB, pmax);
        float alpha = __expf(mB - mn);
        mB = mn;
        lsB *= alpha;
#pragma unroll
        for (int r = 0; r < 4; r++) {
          float ar = __shfl(alpha, (h << 4) + (h << 2) + r);
#pragma unroll
          for (int cbi = 0; cbi < 16; cbi++) oB[cbi][r] *= ar;
        }
      }
      float rs = 0.f;
#pragma unroll
      for (int kt = 0; kt < 2; kt++) {
        float p0 = __expf(sBb[kt][0] - mB);
        float p1 = __expf(sBb[kt][1] - mB);
        float p2 = __expf(sBb[kt][2] - mB);
        float p3 = __expf(sBb[kt][3] - mB);
        rs += (p0 + p1) + (p2 + p3);
        pkBb[kt][0] = (unsigned)f2bf(p0) | ((unsigned)f2bf(p1) << 16);
        pkBb[kt][1] = (unsigned)f2bf(p2) | ((unsigned)f2bf(p3) << 16);
      }
      lsB += rs;
    }
    // ---- PV(b) ----
    {
      union { unsigned int u[4]; shortx8 v; } paA, paB;
      paA.u[0] = pkAb[0][0]; paA.u[1] = pkAb[0][1];
      paA.u[2] = pkAb[1][0]; paA.u[3] = pkAb[1][1];
      paB.u[0] = pkBb[0][0]; paB.u[1] = pkBb[0][1];
      paB.u[2] = pkBb[1][0]; paB.u[3] = pkBb[1][1];
      __builtin_amdgcn_s_setprio(1);
#pragma unroll
      for (int cbi = 0; cbi < 16; cbi++) {
        int row = (cbi << 4) + lo;
        shortx8 vf = *(const shortx8*)(&sMem[vBb + (row << 5) +
                                             ((h ^ ((row >> 1) & 3)) << 3)]);
        oA[cbi] = mfma16(paA.v, vf, oA[cbi]);
        oB[cbi] = mfma16(paB.v, vf, oB[cbi]);
      }
      __builtin_amdgcn_s_setprio(0);
    }
    barrier_raw();   // compute(2j,2j+1) done -> next body may overwrite their bufs
  }

  // reduce per-lane partial lsums across the 4 h-lanes of each q (once)
  lsA += __shfl_xor(lsA, 16);
  lsA += __shfl_xor(lsA, 32);
  lsB += __shfl_xor(lsB, 16);
  lsB += __shfl_xor(lsB, 32);

  float rlA[4], rlB[4];
#pragma unroll
  for (int r = 0; r < 4; r++) {
    rlA[r] = 1.f / __shfl(lsA, (h << 4) + (h << 2) + r);
    rlB[r] = 1.f / __shfl(lsB, (h << 4) + (h << 2) + r);
  }
  unsigned short* ab = attn_t + (size_t)b * NN * CC;
  unsigned short* ow = &sMem[w << 12];   // 8KB (4096 shorts) per wave x 8 waves = 64KB (K bufs)

  // ---- epilogue round A ----
#pragma unroll
  for (int cbi = 0; cbi < 16; cbi++) {
#pragma unroll
    for (int r = 0; r < 4; r++) {
      int q = (h << 2) + r;
      int c = (cbi << 4) + lo;
      int sw = (q ^ (q >> 3)) & 7;
      ow[(q << 8) + (((c >> 3) ^ sw) << 3) + (lo & 7)] = f2bf(oA[cbi][r] * rlA[r]);
    }
  }
  bar_lds();
#pragma unroll
  for (int it = 0; it < 8; it++) {
    int q = (it << 1) + (l >> 5);
    int gc = l & 31;
    int sw = (q ^ (q >> 3)) & 7;
    ushortx8 vv = *(const ushortx8*)(&ow[(q << 8) + ((gc ^ sw) << 3)]);
    *(ushortx8*)(ab + (size_t)(qbase + q) * CC + (gc << 3)) = vv;
  }
  bar_lds();
  // ---- epilogue round B ----
#pragma unroll
  for (int cbi = 0; cbi < 16; cbi++) {
#pragma unroll
    for (int r = 0; r < 4; r++) {
      int q = (h << 2) + r;
      int c = (cbi << 4) + lo;
      int sw = (q ^ (q >> 3)) & 7;
      ow[(q << 8) + (((c >> 3) ^ sw) << 3) + (lo & 7)] = f2bf(oB[cbi][r] * rlB[r]);
    }
  }
  bar_lds();
#pragma unroll
  for (int it = 0; it < 8; it++) {
    int q = (it << 1) + (l >> 5);
    int gc = l & 31;
    int sw = (q ^ (q >> 3)) & 7;
    ushortx8 vv = *(const ushortx8*)(&ow[(q << 8) + ((gc ^ sw) << 3)]);
    *(ushortx8*)(ab + (size_t)(qbase + 16 + q) * CC + (gc << 3)) = vv;
  }
}

// ---------------- Out projection v2: LDS-staged + coalesced f32 store via repack ----------------
__global__ __launch_bounds__(512, 4) void outproj_gemm(const unsigned short* __restrict__ attn_t,
                                                       const unsigned short* __restrict__ wo_bf,
                                                       const float* __restrict__ bo,
                                                       const float* __restrict__ x,
                                                       float* __restrict__ out) {
  __shared__ __align__(16) unsigned short sM[32768];   // 64KB
  __shared__ __align__(16) float sRepF[16 * 132];      // 528B rows (16B-mult)
  int rb = blockIdx.x, b = blockIdx.y;
  int t = threadIdx.x, w = t >> 6, l = t & 63, lo = l & 15, h = l >> 4;
  int rowg = w >> 1, colg = w & 1;
  const unsigned short* A = attn_t + ((size_t)b * NN + rb * 128) * CC;

  int srow_w = w * 2 + (l >> 5);
  int schunk = l & 31;

#pragma unroll
  for (int i = 0; i < 8; i++) {
    int row = i * 16 + srow_w;
    gload16(A + (size_t)row * CC + ((schunk ^ (row & 7)) << 3),
            &sM[(i * 16 + w * 2) << 8]);
  }
  asm volatile("s_waitcnt vmcnt(0)" ::: "memory");
  barrier_raw();

  shortx8 a[2][8];
#pragma unroll
  for (int i = 0; i < 2; i++) {
    int row = rowg * 32 + i * 16 + lo;
#pragma unroll
    for (int ch = 0; ch < 8; ch++)
      a[i][ch] = *(const shortx8*)(&sM[(row << 8) + (((ch * 4 + h) ^ (row & 7)) << 3)]);
  }
  bar_lds();

#pragma unroll
  for (int i = 0; i < 4; i++) {
    int row = i * 16 + srow_w;
    gload16(wo_bf + (size_t)row * CC + ((schunk ^ (row & 7)) << 3),
            &sM[(i * 16 + w * 2) << 8]);
  }

  floatx4 zero4 = {0.f, 0.f, 0.f, 0.f};
  for (int c = 0; c < 4; c++) {
    int cb = (c & 1) << 14;
    if (c < 3) {
      int nb = ((c + 1) & 1) << 14;
#pragma unroll
      for (int i = 0; i < 4; i++) {
        int row = i * 16 + srow_w;
        gload16(wo_bf + (size_t)((c + 1) * 64 + row) * CC + ((schunk ^ (row & 7)) << 3),
                &sM[nb + ((i * 16 + w * 2) << 8)]);
      }
      asm volatile("s_waitcnt vmcnt(4)" ::: "memory");
    } else {
      asm volatile("s_waitcnt vmcnt(0)" ::: "memory");
    }
    barrier_raw();

    floatx4 acc[2][2];
    acc[0][0] = zero4; acc[0][1] = zero4; acc[1][0] = zero4; acc[1][1] = zero4;
    int r0 = colg * 32 + lo, r1 = colg * 32 + 16 + lo;
    __builtin_amdgcn_s_setprio(1);
#pragma unroll
    for (int ch = 0; ch < 8; ch++) {
      shortx8 b0 = *(const shortx8*)(&sM[cb + (r0 << 8) + (((ch * 4 + h) ^ (r0 & 7)) << 3)]);
      shortx8 b1 = *(const shortx8*)(&sM[cb + (r1 << 8) + (((ch * 4 + h) ^ (r1 & 7)) << 3)]);
      acc[0][0] = mfma16(a[0][ch], b0, acc[0][0]);
      acc[0][1] = mfma16(a[0][ch], b1, acc[0][1]);
      acc[1][0] = mfma16(a[1][ch], b0, acc[1][0]);
      acc[1][1] = mfma16(a[1][ch], b1, acc[1][1]);
    }
    __builtin_amdgcn_s_setprio(0);

    // epilogue: 4 quarters of 16 o-rows, repacked through LDS
#pragma unroll
    for (int quarter = 0; quarter < 4; quarter++) {
      int j = quarter & 1;
      if (colg == (quarter >> 1)) {
        float bias = bo[(c << 6) + quarter * 16 + lo];
#pragma unroll
        for (int i = 0; i < 2; i++) {
          floatx4 val;
#pragma unroll
          for (int r = 0; r < 4; r++) val[r] = acc[i][j][r] + bias;
          *(floatx4*)(&sRepF[lo * 132 + rowg * 32 + i * 16 + h * 4]) = val;
        }
      }
      bar_lds();
      int o_l = t >> 5, nq = (t & 31) << 2;
      floatx4 rep = *(const floatx4*)(&sRepF[o_l * 132 + nq]);
      size_t idx = ((size_t)b * CC + (c << 6) + quarter * 16 + o_l) * NN + rb * 128 + nq;
      floatx4 xr = *(const floatx4*)(x + idx);
#pragma unroll
      for (int r = 0; r < 4; r++) rep[r] += xr[r];
      *(floatx4*)(out + idx) = rep;
      bar_lds();
    }
  }
}

extern "C" void kernel_launch(void* const* d_in, const int* in_sizes, int n_in,
                              void* d_out, int out_size, void* d_ws, size_t ws_size,
                              hipStream_t stream) {
  const float* x  = (const float*)d_in[0];
  const float* gw = (const float*)d_in[1];
  const float* gb = (const float*)d_in[2];
  const float* wq = (const float*)d_in[3];
  const float* bq = (const float*)d_in[4];
  const float* wk = (const float*)d_in[5];
  const float* bk = (const float*)d_in[6];
  const float* wv = (const float*)d_in[7];
  const float* bv = (const float*)d_in[8];
  const float* wo = (const float*)d_in[9];
  const float* bo = (const float*)d_in[10];
  float* out = (float*)d_out;

  char* ws = (char*)d_ws;
  unsigned short* q_t   = (unsigned short*)(ws);                 // 33554432 B
  unsigned short* k_t   = (unsigned short*)(ws + 33554432);      // 33554432 B
  unsigned short* v     = (unsigned short*)(ws + 67108864);      // 33554432 B
  unsigned short* h_t   = (unsigned short*)(ws + 100663296);     // 33554432 B (reused as attn_t)
  unsigned short* wqkv  = (unsigned short*)(ws + 134217728);     // 393216 B
  unsigned short* wo_bf = (unsigned short*)(ws + 134610944);     // 131072 B
  float*          bqkv  = (float*)(ws + 134742016);              // 3072 B
  unsigned short* attn_t = h_t;

  // gn grid: x<32 -> GN(group=x, batch=y); x>=32 -> fused weight conversion (17*64=1088 >= 1027)
  gn_kernel<<<dim3(49, 64), dim3(256), 0, stream>>>(x, gw, gb, h_t,
                                                    wq, bq, wk, bk, wv, bv, wo,
                                                    wqkv, wo_bf, bqkv);
  qkv_gemm<<<dim3(8, 64), dim3(512), 0, stream>>>(h_t, wqkv, bqkv, q_t, k_t, v);
  flash_kernel<<<dim3(256), dim3(512), 0, stream>>>(q_t, k_t, v, attn_t);
  outproj_gemm<<<dim3(8, 64), dim3(512), 0, stream>>>(attn_t, wo_bf, bo, x, out);
}

// Round 19
// 187.869 us; speedup vs baseline: 1.1685x; 1.1685x over previous
//
#include <hip/hip_runtime.h>

// Problem: B=64, C=256, H=W=32 -> N=1024 positions, 32 groups.
// Pipeline: GN(+weight convert fused) -> qkv proj -> attention -> out proj -> residual.
// All matmuls in bf16 MFMA (16x16x32). q scaled by C^-0.5=1/16 folded into wq/bq.

#define BB 64
#define CC 256
#define NN 1024

typedef float  floatx4  __attribute__((ext_vector_type(4)));
typedef short  shortx8  __attribute__((ext_vector_type(8)));
typedef unsigned short ushortx4 __attribute__((ext_vector_type(4)));
typedef unsigned short ushortx8 __attribute__((ext_vector_type(8)));

__device__ __forceinline__ unsigned short f2bf(float f) {
  union { float f; unsigned int u; } cv; cv.f = f;
  unsigned int u = cv.u;
  u += 0x7fffu + ((u >> 16) & 1u);
  return (unsigned short)(u >> 16);
}

__device__ __forceinline__ floatx4 mfma16(shortx8 a, shortx8 b, floatx4 c) {
  return __builtin_amdgcn_mfma_f32_16x16x32_bf16(a, b, c, 0, 0, 0);
}

// async global->LDS, 16B per lane. LDS dest = wave-uniform base + lane*16 (linear);
// swizzling is done on the GLOBAL source address (rule #21: both-sides-or-neither).
__device__ __forceinline__ void gload16(const unsigned short* g, unsigned short* s) {
  __builtin_amdgcn_global_load_lds(
      reinterpret_cast<const __attribute__((address_space(1))) void*>(
          (unsigned long long)g),
      reinterpret_cast<__attribute__((address_space(3))) void*>(
          (unsigned int)(unsigned long long)s),
      16, 0, 0);
}

__device__ __forceinline__ void barrier_raw() {
  asm volatile("" ::: "memory");
  __builtin_amdgcn_s_barrier();
  asm volatile("" ::: "memory");
}

// ds_write -> barrier -> ds_read ordering (cross-lane dep the compiler can't see)
__device__ __forceinline__ void bar_lds() {
  asm volatile("s_waitcnt lgkmcnt(0)" ::: "memory");
  __builtin_amdgcn_sched_barrier(0);
  barrier_raw();
}

// K-tile row permutation (32-key tile): LDS row rho holds key k0 + sigma32(rho),
// sigma32(kt*16 + h*4 + r) = h*8 + kt*4 + r  -> lane (h,lo)'s QK outputs are exactly
// the keys PV's A-fragment needs (k = h*8 + j): P->PV is a pure register rename.
__device__ __forceinline__ int sigma32(int r) {
  return (((r >> 2) & 3) << 3) + (((r >> 4) & 1) << 2) + (r & 3);
}

// ---------------- GroupNorm -> h_t (B, N, C) bf16, with weight-convert fused ----------------
// blocks x<32: GN for (group=x, batch=y). blocks x>=32: weight conversion (1088 slots >= 1027).
__global__ __launch_bounds__(256) void gn_kernel(const float* __restrict__ x,
                                                 const float* __restrict__ gw,
                                                 const float* __restrict__ gb,
                                                 unsigned short* __restrict__ h_t,
                                                 const float* __restrict__ wq, const float* __restrict__ bq,
                                                 const float* __restrict__ wk, const float* __restrict__ bk,
                                                 const float* __restrict__ wv, const float* __restrict__ bv,
                                                 const float* __restrict__ wo,
                                                 unsigned short* __restrict__ wqkv,
                                                 unsigned short* __restrict__ wo_bf,
                                                 float* __restrict__ bqkv) {
  if (blockIdx.x >= 32) {
    // ---- weight conversion path ----
    int cid = (blockIdx.x - 32) * 64 + blockIdx.y;
    int i = cid * 256 + threadIdx.x;
    if (i < 196608) {
      int o = i >> 8, c = i & 255;
      float val;
      if (o < 256)      val = wq[o * 256 + c] * 0.0625f;
      else if (o < 512) val = wk[(o - 256) * 256 + c];
      else              val = wv[(o - 512) * 256 + c];
      wqkv[i] = f2bf(val);
    } else if (i < 262144) {
      int j = i - 196608;
      wo_bf[j] = f2bf(wo[j]);
    } else if (i < 262912) {
      int o = i - 262144;
      float val;
      if (o < 256)      val = bq[o] * 0.0625f;
      else if (o < 512) val = bk[o - 256];
      else              val = bv[o - 512];
      bqkv[o] = val;
    }
    return;
  }
  // ---- GroupNorm path ----
  int g = blockIdx.x, b = blockIdx.y;
  int t = threadIdx.x;
  const float* xb = x + ((size_t)b * CC + g * 8) * NN;

  float vals[8][4];
  float s = 0.f, sq = 0.f;
#pragma unroll
  for (int cc = 0; cc < 8; cc++) {
    floatx4 v4 = *(const floatx4*)(xb + cc * NN + t * 4);
#pragma unroll
    for (int j = 0; j < 4; j++) {
      vals[cc][j] = v4[j];
      s += v4[j];
      sq += v4[j] * v4[j];
    }
  }
#pragma unroll
  for (int d = 1; d < 64; d <<= 1) {
    s  += __shfl_xor(s, d);
    sq += __shfl_xor(sq, d);
  }
  __shared__ float ssum[4], ssq[4];
  int w = t >> 6;
  if ((t & 63) == 0) { ssum[w] = s; ssq[w] = sq; }
  __syncthreads();
  s  = ssum[0] + ssum[1] + ssum[2] + ssum[3];
  sq = ssq[0] + ssq[1] + ssq[2] + ssq[3];
  float mean = s * (1.f / 8192.f);
  float var  = sq * (1.f / 8192.f) - mean * mean;
  float rstd = rsqrtf(var + 1e-5f);

  float gam[8], bet[8];
#pragma unroll
  for (int cc = 0; cc < 8; cc++) {
    float gm = gw[g * 8 + cc] * rstd;
    gam[cc] = gm;
    bet[cc] = gb[g * 8 + cc] - mean * gm;
  }
  unsigned short* hb = h_t + (size_t)b * NN * CC + g * 8;
#pragma unroll
  for (int j = 0; j < 4; j++) {
    ushortx8 pk;
#pragma unroll
    for (int cc = 0; cc < 8; cc++) pk[cc] = f2bf(vals[cc][j] * gam[cc] + bet[cc]);
    *(ushortx8*)(hb + (size_t)(t * 4 + j) * CC) = pk;
  }
}

// ---------------- QKV GEMM v3: LDS-staged, A-frags in registers, q/k repack ----------------
__global__ __launch_bounds__(512, 4) void qkv_gemm(const unsigned short* __restrict__ h_t,
                                                   const unsigned short* __restrict__ wqkv,
                                                   const float* __restrict__ bqkv,
                                                   unsigned short* __restrict__ q_t,
                                                   unsigned short* __restrict__ k_t,
                                                   unsigned short* __restrict__ v) {
  __shared__ __align__(16) unsigned short sM[32768];      // 64KB
  __shared__ __align__(16) unsigned short sRep[32 * 136]; // v repack, 272B rows (16B-mult)
  int rb = blockIdx.x, b = blockIdx.y;
  int t = threadIdx.x, w = t >> 6, l = t & 63, lo = l & 15, h = l >> 4;
  int rowg = w >> 1, colg = w & 1;
  const unsigned short* A = h_t + ((size_t)b * NN + rb * 128) * CC;

  int srow_w = w * 2 + (l >> 5);   // staging row (+ i*16)
  int schunk = l & 31;

  // ---- stage A tile 128x256 ----
#pragma unroll
  for (int i = 0; i < 8; i++) {
    int row = i * 16 + srow_w;
    gload16(A + (size_t)row * CC + ((schunk ^ (row & 7)) << 3),
            &sM[(i * 16 + w * 2) << 8]);
  }
  asm volatile("s_waitcnt vmcnt(0)" ::: "memory");
  barrier_raw();

  // ---- extract A-frags to regs (a[i][ch], rows rowg*32 + i*16 + lo) ----
  shortx8 a[2][8];
#pragma unroll
  for (int i = 0; i < 2; i++) {
    int row = rowg * 32 + i * 16 + lo;
#pragma unroll
    for (int ch = 0; ch < 8; ch++)
      a[i][ch] = *(const shortx8*)(&sM[(row << 8) + (((ch * 4 + h) ^ (row & 7)) << 3)]);
  }
  bar_lds();   // sA fully consumed -> LDS reusable for W

  // ---- stage W chunk 0 into buf 0 ----
#pragma unroll
  for (int i = 0; i < 4; i++) {
    int row = i * 16 + srow_w;
    gload16(wqkv + (size_t)row * CC + ((schunk ^ (row & 7)) << 3),
            &sM[(i * 16 + w * 2) << 8]);
  }

  floatx4 zero4 = {0.f, 0.f, 0.f, 0.f};
  for (int c = 0; c < 12; c++) {
    int cb = (c & 1) << 14;
    if (c < 11) {
      int nb = ((c + 1) & 1) << 14;
#pragma unroll
      for (int i = 0; i < 4; i++) {
        int row = i * 16 + srow_w;
        gload16(wqkv + (size_t)((c + 1) * 64 + row) * CC + ((schunk ^ (row & 7)) << 3),
                &sM[nb + ((i * 16 + w * 2) << 8)]);
      }
      asm volatile("s_waitcnt vmcnt(4)" ::: "memory");
    } else {
      asm volatile("s_waitcnt vmcnt(0)" ::: "memory");
    }
    barrier_raw();   // W chunk c visible to all waves

    floatx4 acc[2][2];
    acc[0][0] = zero4; acc[0][1] = zero4; acc[1][0] = zero4; acc[1][1] = zero4;
    int r0 = colg * 32 + lo, r1 = colg * 32 + 16 + lo;
    __builtin_amdgcn_s_setprio(1);
#pragma unroll
    for (int ch = 0; ch < 8; ch++) {
      shortx8 b0 = *(const shortx8*)(&sM[cb + (r0 << 8) + (((ch * 4 + h) ^ (r0 & 7)) << 3)]);
      shortx8 b1 = *(const shortx8*)(&sM[cb + (r1 << 8) + (((ch * 4 + h) ^ (r1 & 7)) << 3)]);
      acc[0][0] = mfma16(a[0][ch], b0, acc[0][0]);
      acc[0][1] = mfma16(a[0][ch], b1, acc[0][1]);
      acc[1][0] = mfma16(a[1][ch], b0, acc[1][0]);
      acc[1][1] = mfma16(a[1][ch], b1, acc[1][1]);
    }
    __builtin_amdgcn_s_setprio(0);

    // ---- epilogue for chunk c ----
    if (c < 8) {
      unsigned short* dst = (c < 4) ? q_t : k_t;
      bar_lds();                         // all waves done reading W chunk c (cb region)
      unsigned short* sQK = &sM[cb];     // reuse 32KB as [128][72]-short repack buffer
#pragma unroll
      for (int i = 0; i < 2; i++) {
#pragma unroll
        for (int j = 0; j < 2; j++) {
          float bias = bqkv[(c << 6) + colg * 32 + j * 16 + lo];
          int o_l = colg * 32 + j * 16 + lo;
#pragma unroll
          for (int r = 0; r < 4; r++) {
            int n_l = rowg * 32 + i * 16 + h * 4 + r;
            sQK[n_l * 72 + o_l] = f2bf(acc[i][j][r] + bias);
          }
        }
      }
      bar_lds();                         // repack writes visible
#pragma unroll
      for (int p = 0; p < 2; p++) {
        int slot = p * 512 + t;
        int n_l = slot >> 3, sg = (slot & 7) << 3;
        ushortx8 vv = *(const ushortx8*)(&sQK[n_l * 72 + sg]);
        *(ushortx8*)(dst + ((size_t)b * NN + rb * 128 + n_l) * CC + ((c & 3) << 6) + sg) = vv;
      }
      bar_lds();                         // reads done before c+2's staging overwrites cb
    } else {
      int vch0 = (c - 8) << 6;
#pragma unroll
      for (int half = 0; half < 2; half++) {
        if (colg == half) {
#pragma unroll
          for (int i = 0; i < 2; i++) {
#pragma unroll
            for (int j = 0; j < 2; j++) {
              float bias = bqkv[512 + vch0 + half * 32 + j * 16 + lo];
              ushortx4 pk;
#pragma unroll
              for (int r = 0; r < 4; r++) pk[r] = f2bf(acc[i][j][r] + bias);
              *(ushortx4*)(&sRep[(j * 16 + lo) * 136 + rowg * 32 + i * 16 + h * 4]) = pk;
            }
          }
        }
        bar_lds();
        int o_l = t >> 4, nseg = (t & 15) << 3;
        ushortx8 vv = *(const ushortx8*)(&sRep[o_l * 136 + nseg]);
        *(ushortx8*)(v + ((size_t)b * CC + vch0 + half * 32 + o_l) * NN + rb * 128 + nseg) = vv;
        bar_lds();
      }
    }
  }
}

// ---------------- Flash attention v12 (best): triple-buffered K/V (96KB), ONE barrier per tile ----------------
// 8-wave blocks, grid 256 (1 block/CU). K[3]+V[3] 16KB buffers; 3-deep rotation makes the
// buffer overwritten at iter t hold tile t-2 (dead under <=1-iter wave skew) -> the
// end-of-compute barrier is removed; single barrier between stage-wait and compute.
// Per-wave compute/softmax/PV identical to proven v8/v11b. Counted vmcnt(4) (own 4 loads
// for tile t landed; tile t+1's 4 in flight).
__global__ __launch_bounds__(512, 2) void flash_kernel(const unsigned short* __restrict__ q_t,
                                                       const unsigned short* __restrict__ k_t,
                                                       const unsigned short* __restrict__ v,
                                                       unsigned short* __restrict__ attn_t) {
  __shared__ __align__(16) unsigned short sMem[49152];   // 96KB: K0|K1|K2 (8192 shorts ea) @0, V0|V1|V2 @24576
  int bid = blockIdx.x;                       // 0..255
  int wgid = ((bid & 7) << 5) + (bid >> 3);   // bijective XCD swizzle: batch pinned to one XCD
  int b = wgid >> 2, qblk = wgid & 3;
  int t = threadIdx.x, w = t >> 6, l = t & 63, lo = l & 15, h = l >> 4;
  const unsigned short* qtb = q_t + (size_t)b * NN * CC;
  const unsigned short* ktb = k_t + (size_t)b * NN * CC;
  const unsigned short* vb  = v   + (size_t)b * CC * NN;
  int qbase = qblk * 256 + w * 32;            // frag A rows qbase.., frag B rows qbase+16..

  shortx8 qfA[8], qfB[8];
#pragma unroll
  for (int ch = 0; ch < 8; ch++) {
    qfA[ch] = *(const shortx8*)(qtb + (size_t)(qbase + lo) * CC + ch * 32 + h * 8);
    qfB[ch] = *(const shortx8*)(qtb + (size_t)(qbase + 16 + lo) * CC + ch * 32 + h * 8);
  }

  floatx4 zero4 = {0.f, 0.f, 0.f, 0.f};
  floatx4 oA[16], oB[16];
#pragma unroll
  for (int i = 0; i < 16; i++) { oA[i] = zero4; oB[i] = zero4; }
  float mA = -1e30f, lsA = 0.f, mB = -1e30f, lsB = 0.f;   // lsA/lsB are per-lane partials

  // staging geometry (per wave, 4 loads/tile: 2 K + 2 V across 8 waves)
  int krow_l = (w << 2) + (l >> 5);   // + i*2  : K rows w*4 .. w*4+3
  int kchunk = l & 31;
  int vrow_l = (w << 5) + (l >> 2);   // + i*16 : V rows w*32 .. w*32+31
  int vchunk = l & 3;

  // prologue: stage tile 0 into buffer 0
#pragma unroll
  for (int i = 0; i < 2; i++) {
    int row = krow_l + i * 2;
    gload16(ktb + (size_t)sigma32(row) * CC + ((kchunk ^ (row & 7)) << 3),
            &sMem[((w << 2) + i * 2) << 8]);
  }
#pragma unroll
  for (int i = 0; i < 2; i++) {
    int row = vrow_l + i * 16;
    gload16(vb + (size_t)row * NN + ((vchunk ^ ((row >> 1) & 3)) << 3),
            &sMem[24576 + (((w << 5) + i * 16) << 5)]);
  }

  int cur = 0;   // buffer index holding tile kb
  for (int kb = 0; kb < 32; kb++) {
    int kB = cur * 8192;           // K buf base (ushorts)
    int vB = 24576 + cur * 8192;   // V buf base
    if (kb < 31) {
      int nxt = (cur == 2) ? 0 : cur + 1;
      int k0n = (kb + 1) << 5;
#pragma unroll
      for (int i = 0; i < 2; i++) {
        int row = krow_l + i * 2;
        gload16(ktb + (size_t)(k0n + sigma32(row)) * CC + ((kchunk ^ (row & 7)) << 3),
                &sMem[nxt * 8192 + (((w << 2) + i * 2) << 8)]);
      }
#pragma unroll
      for (int i = 0; i < 2; i++) {
        int row = vrow_l + i * 16;
        gload16(vb + (size_t)row * NN + k0n + ((vchunk ^ ((row >> 1) & 3)) << 3),
                &sMem[24576 + nxt * 8192 + (((w << 5) + i * 16) << 5)]);
      }
      asm volatile("s_waitcnt vmcnt(4)" ::: "memory");   // own stage(t) landed; t+1 in flight
    } else {
      asm volatile("s_waitcnt vmcnt(0)" ::: "memory");
    }
    barrier_raw();   // single barrier: all waves' stage(t) visible; skew <= 1 iter

    // ---- QK^T (swapped: A=K rows, B=Q rows); one kf feeds both q-fragments ----
    floatx4 sA[2], sB[2];
#pragma unroll
    for (int i = 0; i < 2; i++) { sA[i] = zero4; sB[i] = zero4; }
    __builtin_amdgcn_s_setprio(1);
#pragma unroll
    for (int kt = 0; kt < 2; kt++) {
      const unsigned short* kp = &sMem[kB + ((kt * 16 + lo) << 8)];
#pragma unroll
      for (int ch = 0; ch < 8; ch++) {
        shortx8 kf = *(const shortx8*)(kp + (((ch * 4 + h) ^ (lo & 7)) << 3));
        sA[kt] = mfma16(kf, qfA[ch], sA[kt]);
        sB[kt] = mfma16(kf, qfB[ch], sB[kt]);
      }
    }
    __builtin_amdgcn_s_setprio(0);

    // ---- softmax frag A: per-lane max check, partial lsum (no DS ops common path) ----
    unsigned int pkA[2][2], pkB[2][2];
    {
      float pmax = fmaxf(fmaxf(fmaxf(sA[0][0], sA[0][1]), fmaxf(sA[0][2], sA[0][3])),
                         fmaxf(fmaxf(sA[1][0], sA[1][1]), fmaxf(sA[1][2], sA[1][3])));
      if (!__all(pmax - mA <= 8.f)) {
        // rare: full per-q reduce so m (and alpha) are uniform across the 4 h-lanes
        pmax = fmaxf(pmax, __shfl_xor(pmax, 16));
        pmax = fmaxf(pmax, __shfl_xor(pmax, 32));
        float mn = fmaxf(mA, pmax);
        float alpha = __expf(mA - mn);
        mA = mn;
        lsA *= alpha;
#pragma unroll
        for (int r = 0; r < 4; r++) {
          float ar = __shfl(alpha, (h << 4) + (h << 2) + r);
#pragma unroll
          for (int cbi = 0; cbi < 16; cbi++) oA[cbi][r] *= ar;
        }
      }
      float rs = 0.f;
#pragma unroll
      for (int kt = 0; kt < 2; kt++) {
        float p0 = __expf(sA[kt][0] - mA);
        float p1 = __expf(sA[kt][1] - mA);
        float p2 = __expf(sA[kt][2] - mA);
        float p3 = __expf(sA[kt][3] - mA);
        rs += (p0 + p1) + (p2 + p3);
        pkA[kt][0] = (unsigned)f2bf(p0) | ((unsigned)f2bf(p1) << 16);
        pkA[kt][1] = (unsigned)f2bf(p2) | ((unsigned)f2bf(p3) << 16);
      }
      lsA += rs;   // per-lane partial (this lane's 8 keys)
    }
    // ---- softmax frag B ----
    {
      float pmax = fmaxf(fmaxf(fmaxf(sB[0][0], sB[0][1]), fmaxf(sB[0][2], sB[0][3])),
                         fmaxf(fmaxf(sB[1][0], sB[1][1]), fmaxf(sB[1][2], sB[1][3])));
      if (!__all(pmax - mB <= 8.f)) {
        pmax = fmaxf(pmax, __shfl_xor(pmax, 16));
        pmax = fmaxf(pmax, __shfl_xor(pmax, 32));
        float mn = fmaxf(mB, pmax);
        float alpha = __expf(mB - mn);
        mB = mn;
        lsB *= alpha;
#pragma unroll
        for (int r = 0; r < 4; r++) {
          float ar = __shfl(alpha, (h << 4) + (h << 2) + r);
#pragma unroll
          for (int cbi = 0; cbi < 16; cbi++) oB[cbi][r] *= ar;
        }
      }
      float rs = 0.f;
#pragma unroll
      for (int kt = 0; kt < 2; kt++) {
        float p0 = __expf(sB[kt][0] - mB);
        float p1 = __expf(sB[kt][1] - mB);
        float p2 = __expf(sB[kt][2] - mB);
        float p3 = __expf(sB[kt][3] - mB);
        rs += (p0 + p1) + (p2 + p3);
        pkB[kt][0] = (unsigned)f2bf(p0) | ((unsigned)f2bf(p1) << 16);
        pkB[kt][1] = (unsigned)f2bf(p2) | ((unsigned)f2bf(p3) << 16);
      }
      lsB += rs;
    }

    // ---- PV: A-fragment = register rename (sigma32 layout); V reads swizzled (2-way free) ----
    {
      union { unsigned int u[4]; shortx8 v; } paA, paB;
      paA.u[0] = pkA[0][0]; paA.u[1] = pkA[0][1];
      paA.u[2] = pkA[1][0]; paA.u[3] = pkA[1][1];
      paB.u[0] = pkB[0][0]; paB.u[1] = pkB[0][1];
      paB.u[2] = pkB[1][0]; paB.u[3] = pkB[1][1];
      __builtin_amdgcn_s_setprio(1);
#pragma unroll
      for (int cbi = 0; cbi < 16; cbi++) {
        int row = (cbi << 4) + lo;
        shortx8 vf = *(const shortx8*)(&sMem[vB + (row << 5) +
                                             ((h ^ ((row >> 1) & 3)) << 3)]);
        oA[cbi] = mfma16(paA.v, vf, oA[cbi]);
        oB[cbi] = mfma16(paB.v, vf, oB[cbi]);
      }
      __builtin_amdgcn_s_setprio(0);
    }
    cur = (cur == 2) ? 0 : cur + 1;
    // no trailing barrier: 3-deep rotation keeps overwritten buffers dead under <=1-iter skew
  }

  // reduce per-lane partial lsums across the 4 h-lanes of each q (once)
  lsA += __shfl_xor(lsA, 16);
  lsA += __shfl_xor(lsA, 32);
  lsB += __shfl_xor(lsB, 16);
  lsB += __shfl_xor(lsB, 32);

  float rlA[4], rlB[4];
#pragma unroll
  for (int r = 0; r < 4; r++) {
    rlA[r] = 1.f / __shfl(lsA, (h << 4) + (h << 2) + r);
    rlB[r] = 1.f / __shfl(lsB, (h << 4) + (h << 2) + r);
  }
  unsigned short* ab = attn_t + (size_t)b * NN * CC;
  unsigned short* ow = &sMem[w << 12];   // 8KB (4096 shorts) per wave x 8 waves = 64KB

  barrier_raw();   // all waves done with final tile's K/V before ow overwrites buffers

  // ---- epilogue round A ----
#pragma unroll
  for (int cbi = 0; cbi < 16; cbi++) {
#pragma unroll
    for (int r = 0; r < 4; r++) {
      int q = (h << 2) + r;
      int c = (cbi << 4) + lo;
      int sw = (q ^ (q >> 3)) & 7;
      ow[(q << 8) + (((c >> 3) ^ sw) << 3) + (lo & 7)] = f2bf(oA[cbi][r] * rlA[r]);
    }
  }
  bar_lds();
#pragma unroll
  for (int it = 0; it < 8; it++) {
    int q = (it << 1) + (l >> 5);
    int gc = l & 31;
    int sw = (q ^ (q >> 3)) & 7;
    ushortx8 vv = *(const ushortx8*)(&ow[(q << 8) + ((gc ^ sw) << 3)]);
    *(ushortx8*)(ab + (size_t)(qbase + q) * CC + (gc << 3)) = vv;
  }
  bar_lds();
  // ---- epilogue round B ----
#pragma unroll
  for (int cbi = 0; cbi < 16; cbi++) {
#pragma unroll
    for (int r = 0; r < 4; r++) {
      int q = (h << 2) + r;
      int c = (cbi << 4) + lo;
      int sw = (q ^ (q >> 3)) & 7;
      ow[(q << 8) + (((c >> 3) ^ sw) << 3) + (lo & 7)] = f2bf(oB[cbi][r] * rlB[r]);
    }
  }
  bar_lds();
#pragma unroll
  for (int it = 0; it < 8; it++) {
    int q = (it << 1) + (l >> 5);
    int gc = l & 31;
    int sw = (q ^ (q >> 3)) & 7;
    ushortx8 vv = *(const ushortx8*)(&ow[(q << 8) + ((gc ^ sw) << 3)]);
    *(ushortx8*)(ab + (size_t)(qbase + 16 + q) * CC + (gc << 3)) = vv;
  }
}

// ---------------- Out projection v2: LDS-staged + coalesced f32 store via repack ----------------
__global__ __launch_bounds__(512, 4) void outproj_gemm(const unsigned short* __restrict__ attn_t,
                                                       const unsigned short* __restrict__ wo_bf,
                                                       const float* __restrict__ bo,
                                                       const float* __restrict__ x,
                                                       float* __restrict__ out) {
  __shared__ __align__(16) unsigned short sM[32768];   // 64KB
  __shared__ __align__(16) float sRepF[16 * 132];      // 528B rows (16B-mult)
  int rb = blockIdx.x, b = blockIdx.y;
  int t = threadIdx.x, w = t >> 6, l = t & 63, lo = l & 15, h = l >> 4;
  int rowg = w >> 1, colg = w & 1;
  const unsigned short* A = attn_t + ((size_t)b * NN + rb * 128) * CC;

  int srow_w = w * 2 + (l >> 5);
  int schunk = l & 31;

#pragma unroll
  for (int i = 0; i < 8; i++) {
    int row = i * 16 + srow_w;
    gload16(A + (size_t)row * CC + ((schunk ^ (row & 7)) << 3),
            &sM[(i * 16 + w * 2) << 8]);
  }
  asm volatile("s_waitcnt vmcnt(0)" ::: "memory");
  barrier_raw();

  shortx8 a[2][8];
#pragma unroll
  for (int i = 0; i < 2; i++) {
    int row = rowg * 32 + i * 16 + lo;
#pragma unroll
    for (int ch = 0; ch < 8; ch++)
      a[i][ch] = *(const shortx8*)(&sM[(row << 8) + (((ch * 4 + h) ^ (row & 7)) << 3)]);
  }
  bar_lds();

#pragma unroll
  for (int i = 0; i < 4; i++) {
    int row = i * 16 + srow_w;
    gload16(wo_bf + (size_t)row * CC + ((schunk ^ (row & 7)) << 3),
            &sM[(i * 16 + w * 2) << 8]);
  }

  floatx4 zero4 = {0.f, 0.f, 0.f, 0.f};
  for (int c = 0; c < 4; c++) {
    int cb = (c & 1) << 14;
    if (c < 3) {
      int nb = ((c + 1) & 1) << 14;
#pragma unroll
      for (int i = 0; i < 4; i++) {
        int row = i * 16 + srow_w;
        gload16(wo_bf + (size_t)((c + 1) * 64 + row) * CC + ((schunk ^ (row & 7)) << 3),
                &sM[nb + ((i * 16 + w * 2) << 8)]);
      }
      asm volatile("s_waitcnt vmcnt(4)" ::: "memory");
    } else {
      asm volatile("s_waitcnt vmcnt(0)" ::: "memory");
    }
    barrier_raw();

    floatx4 acc[2][2];
    acc[0][0] = zero4; acc[0][1] = zero4; acc[1][0] = zero4; acc[1][1] = zero4;
    int r0 = colg * 32 + lo, r1 = colg * 32 + 16 + lo;
    __builtin_amdgcn_s_setprio(1);
#pragma unroll
    for (int ch = 0; ch < 8; ch++) {
      shortx8 b0 = *(const shortx8*)(&sM[cb + (r0 << 8) + (((ch * 4 + h) ^ (r0 & 7)) << 3)]);
      shortx8 b1 = *(const shortx8*)(&sM[cb + (r1 << 8) + (((ch * 4 + h) ^ (r1 & 7)) << 3)]);
      acc[0][0] = mfma16(a[0][ch], b0, acc[0][0]);
      acc[0][1] = mfma16(a[0][ch], b1, acc[0][1]);
      acc[1][0] = mfma16(a[1][ch], b0, acc[1][0]);
      acc[1][1] = mfma16(a[1][ch], b1, acc[1][1]);
    }
    __builtin_amdgcn_s_setprio(0);

    // epilogue: 4 quarters of 16 o-rows, repacked through LDS
#pragma unroll
    for (int quarter = 0; quarter < 4; quarter++) {
      int j = quarter & 1;
      if (colg == (quarter >> 1)) {
        float bias = bo[(c << 6) + quarter * 16 + lo];
#pragma unroll
        for (int i = 0; i < 2; i++) {
          floatx4 val;
#pragma unroll
          for (int r = 0; r < 4; r++) val[r] = acc[i][j][r] + bias;
          *(floatx4*)(&sRepF[lo * 132 + rowg * 32 + i * 16 + h * 4]) = val;
        }
      }
      bar_lds();
      int o_l = t >> 5, nq = (t & 31) << 2;
      floatx4 rep = *(const floatx4*)(&sRepF[o_l * 132 + nq]);
      size_t idx = ((size_t)b * CC + (c << 6) + quarter * 16 + o_l) * NN + rb * 128 + nq;
      floatx4 xr = *(const floatx4*)(x + idx);
#pragma unroll
      for (int r = 0; r < 4; r++) rep[r] += xr[r];
      *(floatx4*)(out + idx) = rep;
      bar_lds();
    }
  }
}

extern "C" void kernel_launch(void* const* d_in, const int* in_sizes, int n_in,
                              void* d_out, int out_size, void* d_ws, size_t ws_size,
                              hipStream_t stream) {
  const float* x  = (const float*)d_in[0];
  const float* gw = (const float*)d_in[1];
  const float* gb = (const float*)d_in[2];
  const float* wq = (const float*)d_in[3];
  const float* bq = (const float*)d_in[4];
  const float* wk = (const float*)d_in[5];
  const float* bk = (const float*)d_in[6];
  const float* wv = (const float*)d_in[7];
  const float* bv = (const float*)d_in[8];
  const float* wo = (const float*)d_in[9];
  const float* bo = (const float*)d_in[10];
  float* out = (float*)d_out;

  char* ws = (char*)d_ws;
  unsigned short* q_t   = (unsigned short*)(ws);                 // 33554432 B
  unsigned short* k_t   = (unsigned short*)(ws + 33554432);      // 33554432 B
  unsigned short* v     = (unsigned short*)(ws + 67108864);      // 33554432 B
  unsigned short* h_t   = (unsigned short*)(ws + 100663296);     // 33554432 B (reused as attn_t)
  unsigned short* wqkv  = (unsigned short*)(ws + 134217728);     // 393216 B
  unsigned short* wo_bf = (unsigned short*)(ws + 134610944);     // 131072 B
  float*          bqkv  = (float*)(ws + 134742016);              // 3072 B
  unsigned short* attn_t = h_t;

  // gn grid: x<32 -> GN(group=x, batch=y); x>=32 -> fused weight conversion (17*64=1088 >= 1027)
  gn_kernel<<<dim3(49, 64), dim3(256), 0, stream>>>(x, gw, gb, h_t,
                                                    wq, bq, wk, bk, wv, bv, wo,
                                                    wqkv, wo_bf, bqkv);
  qkv_gemm<<<dim3(8, 64), dim3(512), 0, stream>>>(h_t, wqkv, bqkv, q_t, k_t, v);
  flash_kernel<<<dim3(256), dim3(512), 0, stream>>>(q_t, k_t, v, attn_t);
  outproj_gemm<<<dim3(8, 64), dim3(512), 0, stream>>>(attn_t, wo_bf, bo, x, out);
}